// Round 20
// baseline (524.748 us; speedup 1.0000x reference)
//
#include <hip/hip_runtime.h>

#define NFEAT 64

__device__ __forceinline__ float bf16_to_f(unsigned short h) {
    return __uint_as_float(((unsigned int)h) << 16);
}

// Edge index read: int64 (is64=1) or int32 layout.
__device__ __forceinline__ int get_idx(const void* p, int i, int is64) {
    return is64 ? (int)((const long long*)p)[i] : ((const int*)p)[i];
}

__global__ void v20_zero(int* __restrict__ w, int n_words) {
    int i = blockIdx.x * blockDim.x + threadIdx.x;
    int stride = gridDim.x * blockDim.x;
    for (; i < n_words; i += stride) w[i] = 0;
}

// flags[0] = feat mode (0=bf16, 1=f32); flags[1] = is64 for edge arrays.
__global__ void v20_probe(const unsigned int* __restrict__ e1_raw,
                          const void* __restrict__ feat_raw,
                          int* __restrict__ flags) {
    __shared__ int s_odd, bf_bad, bf_some;
    int t = threadIdx.x;
    if (t == 0) { s_odd = 0; bf_bad = 0; bf_some = 0; }
    __syncthreads();
    for (int w = 2 * t + 1; w < 16384; w += 512)
        if (e1_raw[w] != 0u) atomicOr(&s_odd, 1);
    const unsigned short* fu = (const unsigned short*)feat_raw;
    for (int i = t; i < 4096; i += 256) {
        float v = fabsf(bf16_to_f(fu[i]));
        if (!(v < 16.0f)) atomicOr(&bf_bad, 1);
        if (v > 0.25f && v < 16.0f) atomicOr(&bf_some, 1);
    }
    __syncthreads();
    if (t == 0) {
        int bf_sane = (bf_bad == 0 && bf_some) ? 1 : 0;
        flags[0] = bf_sane ? 0 : 1;       // feat: f32 unless provably bf16 (R17: f32)
        flags[1] = (s_odd == 0) ? 1 : 0;  // edge layout
    }
}

__global__ void v20_deg(const void* __restrict__ esrc, const void* __restrict__ edst,
                        const int* __restrict__ flags,
                        int* __restrict__ deg_out, int* __restrict__ deg_in,
                        int E, int n_src, int n_dst) {
    int i = blockIdx.x * blockDim.x + threadIdx.x;
    if (i >= E) return;
    int is64 = flags[1];
    int s = get_idx(esrc, i, is64);
    int d = get_idx(edst, i, is64);
    if ((unsigned)s < (unsigned)n_src) atomicAdd(&deg_out[s], 1);
    if ((unsigned)d < (unsigned)n_dst) atomicAdd(&deg_in[d], 1);
}

__global__ void v20_norm(const int* __restrict__ deg_out, const int* __restrict__ deg_in,
                         float* __restrict__ nsrc, float* __restrict__ ndst,
                         int n_src, int n_dst) {
    int i = blockIdx.x * blockDim.x + threadIdx.x;
    if (i < n_src) nsrc[i] = rsqrtf(fmaxf((float)deg_out[i], 1.0f));
    if (i < n_dst) ndst[i] = rsqrtf(fmaxf((float)deg_in[i], 1.0f));
}

// One wave per edge, lane=feature; feat read per mode; guarded.
__global__ void v20_scatter(const void* __restrict__ feat_raw,
                            const void* __restrict__ esrc, const void* __restrict__ edst,
                            const int* __restrict__ flags,
                            const float* __restrict__ nsrc,
                            float* __restrict__ accum,
                            int E, int n_src, int n_dst) {
    int gid  = blockIdx.x * blockDim.x + threadIdx.x;
    int edge = gid >> 6;
    int lane = threadIdx.x & 63;
    if (edge >= E) return;
    int mode = flags[0];
    int is64 = flags[1];
    int src = get_idx(esrc, edge, is64);
    int dst = get_idx(edst, edge, is64);
    if ((unsigned)src >= (unsigned)n_src) return;
    if ((unsigned)dst >= (unsigned)n_dst) return;
    float fv;
    if (mode == 1) fv = ((const float*)feat_raw)[src * NFEAT + lane];
    else           fv = bf16_to_f(((const unsigned short*)feat_raw)[src * NFEAT + lane]);
    atomicAdd(&accum[dst * NFEAT + lane], fv * nsrc[src]);
}

// OUTPUT IS FLOAT32 — reference output dtype is float32; harness maps
// float32 -> float*. (R18/R19's bf16 writes of a correct accum scored the
// 1.902 u16-pair-garbage signature; R6's f32 writes only NaN'd because feat
// was misread as bf16 back then.)
__global__ void v20_final(const float* __restrict__ accum,
                          const float* __restrict__ ndst,
                          float* __restrict__ out, int n) {
    int i = blockIdx.x * blockDim.x + threadIdx.x;
    if (i < n) out[i] = accum[i] * ndst[i >> 6];
}

extern "C" void kernel_launch(void* const* d_in, const int* in_sizes, int n_in,
                              void* d_out, int out_size, void* d_ws, size_t ws_size,
                              hipStream_t stream) {
    const void* feat = d_in[0];   // f32 (probe-confirmed each run)
    const void* e1   = d_in[1];   // edge_src (R16 trap: contains >=50000)
    const void* e2   = d_in[2];   // edge_dst
    float* out = (float*)d_out;   // f32 output

    const int n_src = in_sizes[0] / NFEAT;   // 100000
    const int E     = in_sizes[1];           // 1250000
    const int n_dst = out_size / NFEAT;      // 50000

    // ws: [flags 4 i32][deg_out n_src][deg_in n_dst][nsrc n_src][ndst n_dst]
    //     [accum n_dst*64 f32]  (~14.2 MB, proven mapped)
    char* ws = (char*)d_ws;
    size_t off = 0;
    int*   flags   = (int*)(ws + off);   off += 16;
    int*   deg_out = (int*)(ws + off);   off += (size_t)n_src * 4;
    int*   deg_in  = (int*)(ws + off);   off += (size_t)n_dst * 4;
    float* nsrc    = (float*)(ws + off); off += (size_t)n_src * 4;
    float* ndst    = (float*)(ws + off); off += (size_t)n_dst * 4;
    float* accum   = (float*)(ws + off); off += (size_t)n_dst * NFEAT * 4;

    const int B = 256;
    v20_zero<<<1024, B, 0, stream>>>((int*)ws, (int)(off / 4));

    v20_probe<<<1, B, 0, stream>>>((const unsigned int*)e1, feat, flags);

    v20_deg<<<(E + B - 1) / B, B, 0, stream>>>(e1, e2, flags, deg_out, deg_in,
                                               E, n_src, n_dst);

    int nmax = n_src > n_dst ? n_src : n_dst;
    v20_norm<<<(nmax + B - 1) / B, B, 0, stream>>>(deg_out, deg_in, nsrc, ndst,
                                                   n_src, n_dst);

    long long sthreads = (long long)E * 64;
    v20_scatter<<<(int)((sthreads + B - 1) / B), B, 0, stream>>>(feat, e1, e2, flags,
                                                                 nsrc, accum,
                                                                 E, n_src, n_dst);

    v20_final<<<(out_size + B - 1) / B, B, 0, stream>>>(accum, ndst, out, out_size);
}